// Round 8
// baseline (532.430 us; speedup 1.0000x reference)
//
#include <hip/hip_runtime.h>
#include <cstdio>

// ---------------------------------------------------------------------------
// GraphMessagePassing. Round-8: edge MLP on the MFMA pipe with f16 hi/lo
// split (3 MFMAs per logical MFMA; error ~2^-21, i.e. f32-grade).
//  - wave = 16-edge M-tile; 64 edges / 256-thr block; 4 N-tiles of
//    v_mfma_f32_16x16x32_f16; 60 MFMA/wave vs 4608 f32-FMA-cycles before
//  - A-frags: per-lane 16B loads from pre-split nodef hi/lo planes (k-contig
//    fragment layout: row=lane&15, k=(lane>>4)*8+j); edgef split in-kernel
//  - B-frags: 16B loads from pre-transposed/split W^T planes (pre-kernel)
//  - layer1->layer2 transpose via padded LDS H tile (stride 72, 1 barrier)
//  - epilogue: +b2, 64B-segment coalesced atomics (unchanged scheme)
// Node kernel: unchanged from R7 (known-good).
// ---------------------------------------------------------------------------

typedef _Float16 f16;
typedef f16  f16x8 __attribute__((ext_vector_type(8)));
typedef f16  f16x4 __attribute__((ext_vector_type(4)));
typedef float f32x4 __attribute__((ext_vector_type(4)));

#define MFMA16(a, b, c) __builtin_amdgcn_mfma_f32_16x16x32_f16(a, b, c, 0, 0, 0)

// ---- pre-kernel: split node features into f16 hi/lo planes ---------------
__global__ void conv_features(const float* __restrict__ x,
                              f16* __restrict__ xh, f16* __restrict__ xl,
                              int n4) {
    int i = blockIdx.x * blockDim.x + threadIdx.x;
    if (i >= n4) return;
    float4 v = ((const float4*)x)[i];
    float vv[4] = {v.x, v.y, v.z, v.w};
    f16x4 hi, lo;
    #pragma unroll
    for (int j = 0; j < 4; ++j) {
        f16 h = (f16)vv[j];
        hi[j] = h;
        lo[j] = (f16)(vv[j] - (float)h);
    }
    ((f16x4*)xh)[i] = hi;
    ((f16x4*)xl)[i] = lo;
}

// ---- pre-kernel: transpose + split weights: W1^T[64][96] (k-pad), W2^T[64][64]
__global__ void conv_weights(const float* __restrict__ w1,
                             const float* __restrict__ w2,
                             f16* __restrict__ w1th, f16* __restrict__ w1tl,
                             f16* __restrict__ w2th, f16* __restrict__ w2tl) {
    int idx = blockIdx.x * blockDim.x + threadIdx.x;
    if (idx < 64 * 96) {
        int c = idx / 96, k = idx % 96;
        float v = (k < 80) ? w1[k * 64 + c] : 0.f;
        f16 h = (f16)v;
        w1th[c * 96 + k] = h;
        w1tl[c * 96 + k] = (f16)(v - (float)h);
    } else if (idx < 64 * 96 + 64 * 64) {
        int t = idx - 64 * 96;
        int c = t / 64, k = t % 64;
        float v = w2[k * 64 + c];
        f16 h = (f16)v;
        w2th[c * 64 + k] = h;
        w2tl[c * 64 + k] = (f16)(v - (float)h);
    }
}

// ---- edge kernel: MFMA f16-split --------------------------------------------
__global__ __launch_bounds__(256)
void GraphMessagePassing_5952824672257_kernel(
    const f16* __restrict__ nh, const f16* __restrict__ nl,   // [N,64] hi/lo
    const float* __restrict__ edgef,                          // [E,16] f32
    const int*  __restrict__ eidx,                            // [2,E]
    const f16* __restrict__ w1th, const f16* __restrict__ w1tl, // [64][96]
    const f16* __restrict__ w2th, const f16* __restrict__ w2tl, // [64][64]
    const float* __restrict__ b1, const float* __restrict__ b2,
    float* __restrict__ agg, int n_edges, int n_nodes)
{
    __shared__ f16 Hhi[64 * 72];   // [64 e][72 pad] hidden hi
    __shared__ f16 Hlo[64 * 72];

    const int lane = threadIdx.x & 63;
    const int wid  = threadIdx.x >> 6;
    const int r16  = lane & 15;          // A-row / B-col / C-col index
    const int g    = lane >> 4;          // k-group
    const long base = (long)blockIdx.x * 64 + wid * 16;

    // src row for this lane's A-row (edge base + r16)
    long es = base + r16;
    if (es >= n_edges) es = n_edges - 1;
    int s = eidx[es];
    if ((unsigned)s >= (unsigned)n_nodes) s = 0;

    // dsts for the 4 C-rows this lane owns: e = base + g*4 + reg
    int  dstv[4];
    bool val[4];
    #pragma unroll
    for (int reg = 0; reg < 4; ++reg) {
        long ee = base + g * 4 + reg;
        val[reg] = ee < n_edges;
        long ec = val[reg] ? ee : n_edges - 1;
        int d = eidx[(size_t)n_edges + ec];
        if ((unsigned)d >= (unsigned)n_nodes) d = 0;
        dstv[reg] = d;
    }

    // ---- GEMM1: C1[16e][64ch] = X[16e][96k] @ W1[96k][64ch]
    f32x4 acc[4] = {{0.f,0.f,0.f,0.f},{0.f,0.f,0.f,0.f},
                    {0.f,0.f,0.f,0.f},{0.f,0.f,0.f,0.f}};

    #pragma unroll
    for (int kt = 0; kt < 2; ++kt) {             // k 0..63 from node planes
        const int k0 = kt * 32 + g * 8;
        f16x8 ahi = *(const f16x8*)&nh[(size_t)s * 64 + k0];
        f16x8 alo = *(const f16x8*)&nl[(size_t)s * 64 + k0];
        #pragma unroll
        for (int nt = 0; nt < 4; ++nt) {
            const int c = nt * 16 + r16;
            f16x8 bhi = *(const f16x8*)&w1th[c * 96 + k0];
            f16x8 blo = *(const f16x8*)&w1tl[c * 96 + k0];
            acc[nt] = MFMA16(ahi, bhi, acc[nt]);
            acc[nt] = MFMA16(ahi, blo, acc[nt]);
            acc[nt] = MFMA16(alo, bhi, acc[nt]);
        }
    }
    {   // kt 2: k 64..95 — g<2 from edgef (split in-kernel), g>=2 zero-pad
        f16x8 ahi = {}; f16x8 alo = {};
        if (g < 2) {
            const float* ep = edgef + (size_t)es * 16 + g * 8;
            float4 v0 = *(const float4*)(ep);
            float4 v1 = *(const float4*)(ep + 4);
            float xv[8] = {v0.x, v0.y, v0.z, v0.w, v1.x, v1.y, v1.z, v1.w};
            #pragma unroll
            for (int j = 0; j < 8; ++j) {
                f16 h = (f16)xv[j];
                ahi[j] = h;
                alo[j] = (f16)(xv[j] - (float)h);
            }
        }
        const int k0 = 64 + g * 8;
        #pragma unroll
        for (int nt = 0; nt < 4; ++nt) {
            const int c = nt * 16 + r16;
            f16x8 bhi = *(const f16x8*)&w1th[c * 96 + k0];
            f16x8 blo = *(const f16x8*)&w1tl[c * 96 + k0];
            acc[nt] = MFMA16(ahi, bhi, acc[nt]);
            acc[nt] = MFMA16(ahi, blo, acc[nt]);
            acc[nt] = MFMA16(alo, bhi, acc[nt]);
        }
    }

    // ---- +b1, relu, f16-split -> H tile (wave-private rows)
    const int ebase = wid * 16 + g * 4;
    #pragma unroll
    for (int nt = 0; nt < 4; ++nt) {
        const int ch = nt * 16 + r16;
        const float bv = b1[ch];
        #pragma unroll
        for (int reg = 0; reg < 4; ++reg) {
            float h = fmaxf(acc[nt][reg] + bv, 0.f);
            f16 hh = (f16)h;
            Hhi[(ebase + reg) * 72 + ch] = hh;
            Hlo[(ebase + reg) * 72 + ch] = (f16)(h - (float)hh);
        }
    }
    __syncthreads();   // cheap: one barrier total; removes same-wave DS-order risk

    // ---- GEMM2: C2[16e][64ch] = H[16e][64k] @ W2[64k][64ch]
    f32x4 acc2[4] = {{0.f,0.f,0.f,0.f},{0.f,0.f,0.f,0.f},
                     {0.f,0.f,0.f,0.f},{0.f,0.f,0.f,0.f}};
    const int arow = wid * 16 + r16;
    #pragma unroll
    for (int kt = 0; kt < 2; ++kt) {
        const int k0 = kt * 32 + g * 8;
        f16x8 ahi = *(const f16x8*)&Hhi[arow * 72 + k0];
        f16x8 alo = *(const f16x8*)&Hlo[arow * 72 + k0];
        #pragma unroll
        for (int nt = 0; nt < 4; ++nt) {
            const int c = nt * 16 + r16;
            f16x8 bhi = *(const f16x8*)&w2th[c * 64 + k0];
            f16x8 blo = *(const f16x8*)&w2tl[c * 64 + k0];
            acc2[nt] = MFMA16(ahi, bhi, acc2[nt]);
            acc2[nt] = MFMA16(ahi, blo, acc2[nt]);
            acc2[nt] = MFMA16(alo, bhi, acc2[nt]);
        }
    }

    // ---- +b2, coalesced 64B-segment atomics (4 rows x 16 ch per instr)
    #pragma unroll
    for (int nt = 0; nt < 4; ++nt) {
        const int ch = nt * 16 + r16;
        const float bv = b2[ch];
        #pragma unroll
        for (int reg = 0; reg < 4; ++reg) {
            if (val[reg])
                atomicAdd(agg + (size_t)dstv[reg] * 64 + ch,
                          acc2[nt][reg] + bv);
        }
    }
}

// ---- node phase: unchanged from R7 (known-good) -----------------------------
#define TPB 256

__global__ __launch_bounds__(TPB)
void node_mlp_coop(
    const float* __restrict__ nodef,   // [N,64]
    const float* __restrict__ agg,     // [N,64]
    const float* __restrict__ w1,      // [128,64]
    const float* __restrict__ b1,      // [64]
    const float* __restrict__ w2,      // [64,64]
    const float* __restrict__ b2,      // [64]
    float* __restrict__ out,           // [N,64]
    int n_nodes)
{
    __shared__ float HB[64][65];
    float* __restrict__ Xf = &HB[0][0];

    const int tid  = threadIdx.x;
    const int lane = tid & 63;
    const int wch  = __builtin_amdgcn_readfirstlane(tid >> 6) * 16;

    const long base = (long)blockIdx.x * 64;

    const int r  = tid & 15;
    const int e0 = tid >> 4;
    size_t rows[4];
    #pragma unroll
    for (int i = 0; i < 4; ++i) {
        long row = base + e0 + i * 16;
        if (row >= n_nodes) row = n_nodes - 1;
        if (row < 0) row = 0;
        rows[i] = (size_t)row * 64;
    }

    float h[16];
    #pragma unroll
    for (int c = 0; c < 16; ++c) h[c] = b1[wch + c];

    float pf[4];
    #pragma unroll
    for (int i = 0; i < 4; ++i) pf[i] = nodef[rows[i] + r];
    #pragma unroll
    for (int i = 0; i < 4; ++i) Xf[r * 66 + e0 + i * 16] = pf[i];
    #pragma unroll
    for (int i = 0; i < 4; ++i) pf[i] = nodef[rows[i] + 16 + r];
    __syncthreads();

    #pragma unroll
    for (int kc = 0; kc < 8; ++kc) {
        const int cur = kc & 1;
        #pragma unroll 4
        for (int r2 = 0; r2 < 16; ++r2) {
            const float xk = Xf[cur * 1056 + r2 * 66 + lane];
            const float* __restrict__ wr = w1 + (kc * 16 + r2) * 64 + wch;
            #pragma unroll
            for (int c = 0; c < 16; ++c) h[c] = fmaf(xk, wr[c], h[c]);
        }
        if (kc < 7) {
            #pragma unroll
            for (int i = 0; i < 4; ++i)
                Xf[(cur ^ 1) * 1056 + r * 66 + e0 + i * 16] = pf[i];
            if (kc < 6) {
                const float* __restrict__ src = (kc + 2 < 4) ? nodef : agg;
                const int ko = ((kc + 2) & 3) * 16;
                #pragma unroll
                for (int i = 0; i < 4; ++i) pf[i] = src[rows[i] + ko + r];
            }
            __syncthreads();
        }
    }
    __syncthreads();

    #pragma unroll
    for (int c = 0; c < 16; ++c) HB[lane][wch + c] = fmaxf(h[c], 0.f);
    __syncthreads();

    float m[16];
    #pragma unroll
    for (int c = 0; c < 16; ++c) m[c] = b2[wch + c];
    #pragma unroll 4
    for (int t = 0; t < 64; ++t) {
        const float xt = HB[lane][t];
        const float* __restrict__ wr = w2 + t * 64 + wch;
        #pragma unroll
        for (int c = 0; c < 16; ++c) m[c] = fmaf(xt, wr[c], m[c]);
    }
    __syncthreads();

    #pragma unroll
    for (int c = 0; c < 16; ++c) HB[lane][wch + c] = m[c];
    __syncthreads();

    const int oc  = lane & 15;
    const int er4 = lane >> 4;
    #pragma unroll
    for (int g = 0; g < 16; ++g) {
        const int le = g * 4 + er4;
        const float v = HB[le][wch + oc];
        if (base + le < n_nodes)
            out[(size_t)(base + le) * 64 + wch + oc] = v;
    }
}

extern "C" void kernel_launch(void* const* d_in, const int* in_sizes, int n_in,
                              void* d_out, int out_size, void* d_ws, size_t ws_size,
                              hipStream_t stream) {
    // setup_inputs() order:
    // 0 node_features[N,64] f32, 1 edge_features[E,16] f32, 2 edge_index[2,E] i32,
    // 3 w_m1[80,64], 4 b_m1, 5 w_m2[64,64], 6 b_m2,
    // 7 w_u1[128,64], 8 b_u1, 9 w_u2[64,64], 10 b_u2   (all f32)
    const float* nodef = (const float*)d_in[0];
    const float* edgef = (const float*)d_in[1];
    const int*   eidx  = (const int*)d_in[2];
    const float* w_m1  = (const float*)d_in[3];
    const float* b_m1  = (const float*)d_in[4];
    const float* w_m2  = (const float*)d_in[5];
    const float* b_m2  = (const float*)d_in[6];
    const float* w_u1  = (const float*)d_in[7];
    const float* b_u1  = (const float*)d_in[8];
    const float* w_u2  = (const float*)d_in[9];
    const float* b_u2  = (const float*)d_in[10];
    float* out = (float*)d_out;

    const int n_nodes = out_size / 64;
    const int n_edges = in_sizes[2] / 2;
    if (n_edges <= 0 || n_nodes <= 0) return;

    // workspace layout
    char* wsb = (char*)d_ws;
    float* agg = (float*)wsb;
    size_t o = ((size_t)n_nodes * 64 * 4 + 255) & ~(size_t)255;
    f16* nh = (f16*)(wsb + o); o += (size_t)n_nodes * 64 * 2;
    f16* nl = (f16*)(wsb + o); o += (size_t)n_nodes * 64 * 2;
    f16* w1th = (f16*)(wsb + o); o += 64 * 96 * 2;
    f16* w1tl = (f16*)(wsb + o); o += 64 * 96 * 2;
    f16* w2th = (f16*)(wsb + o); o += 64 * 64 * 2;
    f16* w2tl = (f16*)(wsb + o); o += 64 * 64 * 2;

    fprintf(stderr, "[KL] mfma-f16split E=%d N=%d ws=%zu used=%zu\n",
            n_edges, n_nodes, ws_size, o);
    fflush(stderr);

    hipMemsetAsync(agg, 0, (size_t)n_nodes * 64 * sizeof(float), stream);

    const int n4 = n_nodes * 64 / 4;
    conv_features<<<(n4 + 255) / 256, 256, 0, stream>>>(nodef, nh, nl, n4);
    conv_weights<<<(64 * 96 + 64 * 64 + 255) / 256, 256, 0, stream>>>(
        w_m1, w_m2, w1th, w1tl, w2th, w2tl);

    const int blocks_e = (n_edges + 63) / 64;
    GraphMessagePassing_5952824672257_kernel<<<blocks_e, 256, 0, stream>>>(
        nh, nl, edgef, eidx, w1th, w1tl, w2th, w2tl, b_m1, b_m2,
        agg, n_edges, n_nodes);

    const int blocks_n = (n_nodes + 63) / 64;
    node_mlp_coop<<<blocks_n, TPB, 0, stream>>>(
        nodef, agg, w_u1, b_u1, w_u2, b_u2, out, n_nodes);

    hipError_t le = hipGetLastError();
    fprintf(stderr, "[KL] last=%d(%s)\n", (int)le, hipGetErrorName(le));
    fflush(stderr);
}